// Round 3
// baseline (5277.192 us; speedup 1.0000x reference)
//
#include <hip/hip_runtime.h>
#include <hip/hip_bf16.h>

using bf16 = __hip_bfloat16;

typedef __attribute__((ext_vector_type(8))) short short8;   // 8 bf16 (4 VGPRs) MFMA frag
typedef __attribute__((ext_vector_type(4))) float floatx4;  // MFMA accumulator

#define BB 32
#define TT 48
#define SS 128
#define HH 768
#define VV 28996

__device__ __forceinline__ float sigmoidf_(float x) { return 1.0f / (1.0f + expf(-x)); }
__device__ __forceinline__ float tanhf_(float x) {
    float xx = fminf(fmaxf(x, -15.0f), 15.0f);
    float e = expf(2.0f * xx);
    return (e - 1.0f) / (e + 1.0f);
}

// ---------------------------------------------------------------------------
// Split f32 -> bf16 hi + bf16 lo (lo = rounded residual); combined ~2^-17 rel.
// ---------------------------------------------------------------------------
__device__ __forceinline__ void split1(float v, bf16& h, bf16& l) {
    h = (bf16)v;
    l = (bf16)(v - __bfloat162float(h));
}

// counts (in float4 quads unless noted)
#define XQ    294912   // x:    1536*768/4
#define WIHQ  442368   // Wih:  2304*768/4
#define EQ    786432   // E:    4096*768/4
#define WC1Q  147456   // Wc1:  768*768/4 (compacted from W_ctx[:, :768])
#define WATS  589824   // WatT: 768*768 scalars (transpose)

__global__ __launch_bounds__(256)
void split_ops(const float* __restrict__ x, const float* __restrict__ Wih,
               const float* __restrict__ E, const float* __restrict__ Wctx,
               const float* __restrict__ Watt,
               bf16* __restrict__ xh, bf16* __restrict__ xl,
               bf16* __restrict__ wihh, bf16* __restrict__ wihl,
               bf16* __restrict__ eh, bf16* __restrict__ el,
               bf16* __restrict__ wc1h, bf16* __restrict__ wc1l,
               bf16* __restrict__ wath, bf16* __restrict__ watl)
{
    int idx = blockIdx.x * 256 + threadIdx.x;
    if (idx < XQ + WIHQ + EQ) {
        const float* src; bf16 *dh, *dl; int off;
        if (idx < XQ)            { src = x;   dh = xh;   dl = xl;   off = idx; }
        else if (idx < XQ + WIHQ){ src = Wih; dh = wihh; dl = wihl; off = idx - XQ; }
        else                     { src = E;   dh = eh;   dl = el;   off = idx - XQ - WIHQ; }
        float4 v = ((const float4*)src)[off];
        union { bf16 b[4]; uint2 u; } oh, ol;
        split1(v.x, oh.b[0], ol.b[0]); split1(v.y, oh.b[1], ol.b[1]);
        split1(v.z, oh.b[2], ol.b[2]); split1(v.w, oh.b[3], ol.b[3]);
        ((uint2*)dh)[off] = oh.u; ((uint2*)dl)[off] = ol.u;
    } else if (idx < XQ + WIHQ + EQ + WC1Q) {
        int rem = idx - XQ - WIHQ - EQ;          // j*192 + c4
        int j = rem / 192, c4 = rem - j * 192;
        float4 v = *(const float4*)(Wctx + (size_t)j * 1536 + 4 * c4);
        union { bf16 b[4]; uint2 u; } oh, ol;
        split1(v.x, oh.b[0], ol.b[0]); split1(v.y, oh.b[1], ol.b[1]);
        split1(v.z, oh.b[2], ol.b[2]); split1(v.w, oh.b[3], ol.b[3]);
        ((uint2*)wc1h)[rem] = oh.u; ((uint2*)wc1l)[rem] = ol.u;
    } else if (idx < XQ + WIHQ + EQ + WC1Q + WATS) {
        int rem = idx - XQ - WIHQ - EQ - WC1Q;   // n*768 + k
        int n = rem / 768, k = rem - n * 768;
        float v = Watt[(size_t)k * 768 + n];     // WatT[n][k] = W_att[k][n]
        bf16 h, l; split1(v, h, l);
        wath[rem] = h; watl[rem] = l;
    }
}

// ---------------------------------------------------------------------------
// Repack W_hh and Wc2 (= W_ctx[:, 768:]) as f32 float4 K-major:
// Wf[g][k4][j] = {W_hh[g*768+j][4k4 .. 4k4+3]}   (g<3, k4<192, j<768)
// ---------------------------------------------------------------------------
#define WHHQ 442368   // 3*192*768
#define WC2Q 147456   // 192*768
__global__ __launch_bounds__(256)
void pack_whh(const float* __restrict__ Whh, const float* __restrict__ Wctx,
              float4* __restrict__ Wf, float4* __restrict__ Wc2f)
{
    int idx = blockIdx.x * 256 + threadIdx.x;
    if (idx < WHHQ) {
        int g = idx / (192 * 768);
        int rem = idx - g * (192 * 768);
        int k4 = rem / 768, j = rem - k4 * 768;
        Wf[idx] = *(const float4*)(Whh + (size_t)(g * 768 + j) * 768 + 4 * k4);
    } else if (idx < WHHQ + WC2Q) {
        int rem = idx - WHHQ;
        int k4 = rem / 768, j = rem - k4 * 768;
        Wc2f[rem] = *(const float4*)(Wctx + (size_t)j * 1536 + 768 + 4 * k4);
    }
}

// gbias[b*S+s] = b_att . E[b,s,:]
__global__ __launch_bounds__(256)
void gbias_k(const float* __restrict__ E, const float* __restrict__ batt,
             float* __restrict__ gbias)
{
    int row = blockIdx.x * 4 + (threadIdx.x >> 6);
    int lane = threadIdx.x & 63;
    const float* er = E + (size_t)row * 768;
    float acc = 0.f;
#pragma unroll
    for (int i = 0; i < 12; ++i) acc += er[i * 64 + lane] * batt[i * 64 + lane];
#pragma unroll
    for (int d = 32; d > 0; d >>= 1) acc += __shfl_xor(acc, d);
    if (lane == 0) gbias[row] = acc;
}

// W_pred f32 -> bf16 (logits operand; off the recurrent path, bf16 is safe)
#define WPQ 5567232   // 28996*768/4
__global__ __launch_bounds__(256)
void conv_pred(const float* __restrict__ Wp, bf16* __restrict__ Wpb)
{
    int idx = blockIdx.x * 256 + threadIdx.x;
    if (idx >= WPQ) return;
    float4 v = ((const float4*)Wp)[idx];
    union { bf16 b[4]; uint2 u; } o;
    o.b[0] = (bf16)v.x; o.b[1] = (bf16)v.y; o.b[2] = (bf16)v.z; o.b[3] = (bf16)v.w;
    ((uint2*)Wpb)[idx] = o.u;
}

// ---------------------------------------------------------------------------
// Split-bf16 near-f32 GEMM: C[m,n] = sum_k A[m,k]*B[n,k] (+bias[n]), f32 out.
// A = Ahi+Alo, B = Bhi+Blo; acc += Ahi*Bhi + Ahi*Blo + Alo*Bhi (3x MFMA).
// 128x128 tile, BK=64; M,N multiples of 128 (all call sites). 64KB LDS.
// ---------------------------------------------------------------------------
__global__ __launch_bounds__(256)
void gemm_split(const bf16* __restrict__ Ahi, const bf16* __restrict__ Alo, int lda,
                const bf16* __restrict__ Bhi, const bf16* __restrict__ Blo, int ldb,
                const float* __restrict__ bias,
                float* __restrict__ C, int ldc, int M, int N, int K)
{
    __shared__ __align__(16) char smem[65536];  // Ahi|Alo|Bhi|Blo 16KB each
    const int tid  = threadIdx.x;
    const int lane = tid & 63;
    const int widx = tid >> 6;
    const int wm = widx >> 1, wn = widx & 1;
    const int m0 = blockIdx.y * 128, n0 = blockIdx.x * 128;

    floatx4 acc[4][4];
    const floatx4 fzero = {0.f, 0.f, 0.f, 0.f};
#pragma unroll
    for (int i = 0; i < 4; ++i)
#pragma unroll
        for (int j = 0; j < 4; ++j) acc[i][j] = fzero;

    const int srow = tid >> 3, sslot = tid & 7;

    for (int kb = 0; kb < K; kb += 64) {
        __syncthreads();
        const bf16* mats[4] = {Ahi, Alo, Bhi, Blo};
#pragma unroll
        for (int mt = 0; mt < 4; ++mt) {
            const bf16* base = mats[mt];
            int ld   = (mt < 2) ? lda : ldb;
            int row0 = (mt < 2) ? m0 : n0;
#pragma unroll
            for (int r = 0; r < 4; ++r) {
                int row = r * 32 + srow;
                int c = sslot ^ (row & 7);
                const bf16* gp = base + (size_t)(row0 + row) * ld + kb + c * 8;
                char* lp = smem + mt * 16384 + r * 4096 + widx * 1024;
                __builtin_amdgcn_global_load_lds(
                    (const __attribute__((address_space(1))) void*)gp,
                    (__attribute__((address_space(3))) void*)lp, 16, 0, 0);
            }
        }
        __syncthreads();
#pragma unroll
        for (int kc = 0; kc < 2; ++kc) {
            short8 ah[4], al[4], bh[4], bl[4];
#pragma unroll
            for (int i = 0; i < 4; ++i) {
                int mrow = wm * 64 + i * 16 + (lane & 15);
                int nrow = wn * 64 + i * 16 + (lane & 15);
                int ca = kc * 4 + (lane >> 4);
                int sm = (ca ^ (mrow & 7)) * 16, sn = (ca ^ (nrow & 7)) * 16;
                ah[i] = *(const short8*)(smem +         mrow * 128 + sm);
                al[i] = *(const short8*)(smem + 16384 + mrow * 128 + sm);
                bh[i] = *(const short8*)(smem + 32768 + nrow * 128 + sn);
                bl[i] = *(const short8*)(smem + 49152 + nrow * 128 + sn);
            }
#pragma unroll
            for (int i = 0; i < 4; ++i)
#pragma unroll
                for (int j = 0; j < 4; ++j) {
                    acc[i][j] = __builtin_amdgcn_mfma_f32_16x16x32_bf16(ah[i], bh[j], acc[i][j], 0, 0, 0);
                    acc[i][j] = __builtin_amdgcn_mfma_f32_16x16x32_bf16(ah[i], bl[j], acc[i][j], 0, 0, 0);
                    acc[i][j] = __builtin_amdgcn_mfma_f32_16x16x32_bf16(al[i], bh[j], acc[i][j], 0, 0, 0);
                }
        }
    }
#pragma unroll
    for (int i = 0; i < 4; ++i) {
        int gm0 = m0 + wm * 64 + i * 16 + (lane >> 4) * 4;
#pragma unroll
        for (int j = 0; j < 4; ++j) {
            int gn = n0 + wn * 64 + j * 16 + (lane & 15);
            float bv = bias ? bias[gn] : 0.0f;
#pragma unroll
            for (int r2 = 0; r2 < 4; ++r2)
                C[(size_t)(gm0 + r2) * ldc + gn] = acc[i][j][r2] + bv;
        }
    }
}

// ---------------------------------------------------------------------------
// Plain bf16 MFMA GEMM (m97-style) for the logits: f32 out, N edge handled.
// ---------------------------------------------------------------------------
__global__ __launch_bounds__(256)
void gemm_bt(const bf16* __restrict__ A, int lda,
             const bf16* __restrict__ Bm, int ldb,
             const float* __restrict__ bias,
             float* __restrict__ C, int ldc, int M, int N, int K)
{
    __shared__ __align__(16) char smem[32768];
    const int tid  = threadIdx.x;
    const int lane = tid & 63;
    const int widx = tid >> 6;
    const int wm = widx >> 1, wn = widx & 1;
    const int m0 = blockIdx.y * 128, n0 = blockIdx.x * 128;

    floatx4 acc[4][4];
    const floatx4 fzero = {0.f, 0.f, 0.f, 0.f};
#pragma unroll
    for (int i = 0; i < 4; ++i)
#pragma unroll
        for (int j = 0; j < 4; ++j) acc[i][j] = fzero;

    const int srow = tid >> 3, sslot = tid & 7;

    for (int kb = 0; kb < K; kb += 64) {
        __syncthreads();
#pragma unroll
        for (int r = 0; r < 4; ++r) {
            int mrow = r * 32 + srow;
            int c = sslot ^ (mrow & 7);
            const bf16* gp = A + (size_t)(m0 + mrow) * lda + kb + c * 8;
            char* lp = smem + r * 4096 + widx * 1024;
            __builtin_amdgcn_global_load_lds(
                (const __attribute__((address_space(1))) void*)gp,
                (__attribute__((address_space(3))) void*)lp, 16, 0, 0);
        }
#pragma unroll
        for (int r = 0; r < 4; ++r) {
            int nrow = r * 32 + srow;
            int gn = n0 + nrow; if (gn > N - 1) gn = N - 1;
            int c = sslot ^ (nrow & 7);
            const bf16* gp = Bm + (size_t)gn * ldb + kb + c * 8;
            char* lp = smem + 16384 + r * 4096 + widx * 1024;
            __builtin_amdgcn_global_load_lds(
                (const __attribute__((address_space(1))) void*)gp,
                (__attribute__((address_space(3))) void*)lp, 16, 0, 0);
        }
        __syncthreads();
#pragma unroll
        for (int kc = 0; kc < 2; ++kc) {
            short8 af[4], bfr[4];
#pragma unroll
            for (int i = 0; i < 4; ++i) {
                int mrow = wm * 64 + i * 16 + (lane & 15);
                int nrow = wn * 64 + i * 16 + (lane & 15);
                int ca = kc * 4 + (lane >> 4);
                af[i]  = *(const short8*)(smem +         mrow * 128 + ((ca ^ (mrow & 7)) * 16));
                bfr[i] = *(const short8*)(smem + 16384 + nrow * 128 + ((ca ^ (nrow & 7)) * 16));
            }
#pragma unroll
            for (int i = 0; i < 4; ++i)
#pragma unroll
                for (int j = 0; j < 4; ++j)
                    acc[i][j] = __builtin_amdgcn_mfma_f32_16x16x32_bf16(af[i], bfr[j], acc[i][j], 0, 0, 0);
        }
    }
#pragma unroll
    for (int i = 0; i < 4; ++i) {
        int gm0 = m0 + wm * 64 + i * 16 + (lane >> 4) * 4;
#pragma unroll
        for (int j = 0; j < 4; ++j) {
            int gn = n0 + wn * 64 + j * 16 + (lane & 15);
            if (gn < N) {
                float bv = bias ? bias[gn] : 0.0f;
#pragma unroll
                for (int r2 = 0; r2 < 4; ++r2)
                    C[(size_t)(gm0 + r2) * ldc + gn] = acc[i][j][r2] + bv;
            }
        }
    }
}

// ---------------------------------------------------------------------------
// Sequential decoder, FULL F32 on the recurrent path. One block per batch,
// 768 threads = one per hidden dim j. h in f32 LDS; GEMVs are f32 FMA with
// float4 K-major weights (coalesced 16B/lane).
// ---------------------------------------------------------------------------
__global__ __launch_bounds__(768)
void seq_kernel(const float* __restrict__ gi,     // [B*T][2304]
                const float4* __restrict__ Wf,    // [3][192][768] float4
                const float4* __restrict__ Wc2f,  // [192][768] float4
                const float* __restrict__ G,      // [B*S][768] f32
                const float* __restrict__ F,      // [B*S][768] f32
                const float* __restrict__ gbias,  // [B*S]
                const float* __restrict__ h0,     // [B][768]
                const float* __restrict__ b_hh,   // [2304]
                const float* __restrict__ b_ctx,  // [768]
                bf16* __restrict__ Hseq)          // [B*T][768] bf16
{
    const int b = blockIdx.x;
    const int j = threadIdx.x;
    const int lane = j & 63, wid = j >> 6;  // 12 waves
    __shared__ __align__(16) float h_lds[768];
    __shared__ float sc[128];

    float hreg = h0[b * 768 + j];
    h_lds[j] = hreg;
    const float bhr = b_hh[j];
    const float bhz = b_hh[768 + j];
    const float bhn = b_hh[1536 + j];
    const float bc  = b_ctx[j];

    const float4* Wr = Wf;
    const float4* Wz = Wf + 192 * 768;
    const float4* Wn = Wf + 2 * 192 * 768;
    const float* Gb = G + (size_t)b * SS * HH;
    const float* Fb = F + (size_t)b * SS * HH + j;
    const float* gbb = gbias + b * SS;
    const float4* h4 = (const float4*)h_lds;

    __syncthreads();

    for (int t = 0; t < TT; ++t) {
        const float* gir = gi + (size_t)(b * TT + t) * 2304;
        float ir = gir[j], iz = gir[768 + j], inn = gir[1536 + j];
        float racc = 0.f, zacc = 0.f, nacc = 0.f;
#pragma unroll 4
        for (int k4 = 0; k4 < 192; ++k4) {
            float4 hv = h4[k4];
            float4 wr = Wr[k4 * 768 + j];
            float4 wz = Wz[k4 * 768 + j];
            float4 wn = Wn[k4 * 768 + j];
            racc += wr.x * hv.x + wr.y * hv.y + wr.z * hv.z + wr.w * hv.w;
            zacc += wz.x * hv.x + wz.y * hv.y + wz.z * hv.z + wz.w * hv.w;
            nacc += wn.x * hv.x + wn.y * hv.y + wn.z * hv.z + wn.w * hv.w;
        }
        float r = sigmoidf_(ir + racc + bhr);
        float z = sigmoidf_(iz + zacc + bhz);
        float n = tanhf_(inn + r * (nacc + bhn));
        float ht = (1.0f - z) * n + z * hreg;
        __syncthreads();                 // all gh reads of h_lds done
        h_lds[j] = ht;
        Hseq[(size_t)(b * TT + t) * HH + j] = (bf16)ht;   // logits use post-GRU h
        __syncthreads();
        // scores_s = h_t . G[b,s,:] + (b_att.E fold); wave per s
        for (int s = wid; s < SS; s += 12) {
            const float* grow = Gb + (size_t)s * 768;
            float p0 = 0.f;
#pragma unroll
            for (int i = 0; i < 12; ++i)
                p0 += grow[i * 64 + lane] * h_lds[i * 64 + lane];
#pragma unroll
            for (int d = 32; d > 0; d >>= 1) p0 += __shfl_xor(p0, d);
            if (lane == 0) sc[s] = p0 + gbb[s];
        }
        __syncthreads();
        if (wid == 0) {                  // softmax over 128
            float v0 = sc[lane], v1 = sc[64 + lane];
            float m = fmaxf(v0, v1);
#pragma unroll
            for (int d = 32; d > 0; d >>= 1) m = fmaxf(m, __shfl_xor(m, d));
            float e0 = expf(v0 - m), e1 = expf(v1 - m);
            float ssum = e0 + e1;
#pragma unroll
            for (int d = 32; d > 0; d >>= 1) ssum += __shfl_xor(ssum, d);
            float inv = 1.0f / ssum;
            sc[lane] = e0 * inv;
            sc[64 + lane] = e1 * inv;
        }
        __syncthreads();
        // h_new = tanh( Wc2 @ h_t + sum_s p_s F[b,s,:] + b_ctx )
        float u = bc;
#pragma unroll 4
        for (int k4 = 0; k4 < 192; ++k4) {
            float4 hv = h4[k4];
            float4 wc = Wc2f[k4 * 768 + j];
            u += wc.x * hv.x + wc.y * hv.y + wc.z * hv.z + wc.w * hv.w;
        }
#pragma unroll 8
        for (int s = 0; s < SS; ++s)
            u += sc[s] * Fb[(size_t)s * HH];
        float hn = tanhf_(u);
        __syncthreads();                 // all reads of h_lds/sc done
        h_lds[j] = hn;
        hreg = hn;
        __syncthreads();
    }
}

// ---------------------------------------------------------------------------
extern "C" void kernel_launch(void* const* d_in, const int* in_sizes, int n_in,
                              void* d_out, int out_size, void* d_ws, size_t ws_size,
                              hipStream_t stream)
{
    const float* x      = (const float*)d_in[0];
    const float* h0     = (const float*)d_in[1];
    const float* E      = (const float*)d_in[2];
    const float* W_ih   = (const float*)d_in[3];
    const float* W_hh   = (const float*)d_in[4];
    const float* b_ih   = (const float*)d_in[5];
    const float* b_hh   = (const float*)d_in[6];
    const float* W_pred = (const float*)d_in[7];
    const float* b_pred = (const float*)d_in[8];
    const float* W_att  = (const float*)d_in[9];
    const float* b_att  = (const float*)d_in[10];
    const float* W_ctx  = (const float*)d_in[11];
    const float* b_ctx  = (const float*)d_in[12];
    float* out = (float*)d_out;

    // workspace layout (peak ~80.2MB; Wpredb aliases gi/G/F/Wf after seq)
    char* ws = (char*)d_ws;
    float*  gi    = (float*)(ws);                   // 14,155,776
    float*  G     = (float*)(ws + 14155776);        // 12,582,912
    float*  F     = (float*)(ws + 26738688);        // 12,582,912
    float4* Wf    = (float4*)(ws + 39321600);       //  7,077,888
    float4* Wc2f  = (float4*)(ws + 46399488);       //  2,359,296
    float*  gbias = (float*)(ws + 48758784);        //     16,384
    bf16*   Hseq  = (bf16*)(ws + 48775168);         //  2,359,296
    bf16*   xh    = (bf16*)(ws + 51134464);         //  2,359,296
    bf16*   xl    = (bf16*)(ws + 53493760);         //  2,359,296
    bf16*   wihh  = (bf16*)(ws + 55853056);         //  3,538,944
    bf16*   wihl  = (bf16*)(ws + 59392000);         //  3,538,944
    bf16*   eh    = (bf16*)(ws + 62930944);         //  6,291,456
    bf16*   el    = (bf16*)(ws + 69222400);         //  6,291,456
    bf16*   wath  = (bf16*)(ws + 75513856);         //  1,179,648
    bf16*   watl  = (bf16*)(ws + 76693504);         //  1,179,648
    bf16*   wc1h  = (bf16*)(ws + 77873152);         //  1,179,648
    bf16*   wc1l  = (bf16*)(ws + 79052800);         //  1,179,648  -> end 80,232,448
    bf16*   Wpredb = (bf16*)(ws);                   // 44,537,856 (aliases dead gi/G/F/Wf)

    // 1. splits / packs / b_att fold
    split_ops<<<8832, 256, 0, stream>>>(x, W_ih, E, W_ctx, W_att,
                                        xh, xl, wihh, wihl, eh, el,
                                        wc1h, wc1l, wath, watl);
    pack_whh<<<2304, 256, 0, stream>>>(W_hh, W_ctx, Wf, Wc2f);
    gbias_k<<<1024, 256, 0, stream>>>(E, b_att, gbias);

    // 2. near-f32 precompute GEMMs (split-bf16, f32 out)
    gemm_split<<<dim3(18, 12), 256, 0, stream>>>(
        xh, xl, 768, wihh, wihl, 768, b_ih, gi, 2304, BB * TT, 2304, 768);
    gemm_split<<<dim3(6, 32), 256, 0, stream>>>(
        eh, el, 768, wath, watl, 768, nullptr, G, 768, BB * SS, 768, 768);
    gemm_split<<<dim3(6, 32), 256, 0, stream>>>(
        eh, el, 768, wc1h, wc1l, 768, nullptr, F, 768, BB * SS, 768, 768);

    // 3. sequential recurrence, full f32 (32 independent blocks)
    seq_kernel<<<32, 768, 0, stream>>>(gi, Wf, Wc2f, G, F, gbias,
                                       h0, b_hh, b_ctx, Hseq);

    // 4. W_pred -> bf16 (into now-dead region), then logits GEMM (f32 out)
    conv_pred<<<21747, 256, 0, stream>>>(W_pred, Wpredb);
    gemm_bt<<<dim3(227, 12), 256, 0, stream>>>(
        Hseq, 768, Wpredb, 768, b_pred, out, VV, BB * TT, VV, 768);
}